// Round 2
// baseline (3969.163 us; speedup 1.0000x reference)
//
#include <hip/hip_runtime.h>
#include <hip/hip_bf16.h>

#define N_PTS 8192
#define N_SAMP 2048
#define KNN_K 16
#define NBATCH 4
#define BN_M (NBATCH * N_SAMP * KNN_K)  // 131072

typedef float f32x2 __attribute__((ext_vector_type(2)));

// ---------------------------------------------------------------- FPS
// One block per batch. xyz staged in LDS; each thread's 8 points in registers
// as 4x float2 (v_pk_* packed fp32 on gfx950; bit-identical rounding to
// scalar). Packed u64 argmax key: (f32bits<<32)|~idx so max => farthest,
// ties => smallest index (matches jnp.argmax).
// Reduction: intra-wave butterfly -> lane0 writes red[it&1][wid] -> ONE
// barrier -> every thread serial-maxes the 16 keys (parity double-buffer
// makes the single barrier race-free).
__global__ __launch_bounds__(1024) void fps_kernel(const float* __restrict__ xyz,
                                                   int* __restrict__ fps_idx,
                                                   float* __restrict__ new_xyz) {
#pragma clang fp contract(off)
  __shared__ float xs[N_PTS], ys[N_PTS], zs[N_PTS];
  __shared__ int samp[N_SAMP];
  __shared__ unsigned long long red[2][16];
  const int b = blockIdx.x;
  const int tid = threadIdx.x;
  const int lane = tid & 63;
  const int wid = tid >> 6;
  const float* base = xyz + (size_t)b * N_PTS * 3;
  for (int i = tid; i < N_PTS * 3; i += 1024) {
    float v = base[i];
    int p = i / 3, c = i - p * 3;
    if (c == 0) xs[p] = v; else if (c == 1) ys[p] = v; else zs[p] = v;
  }
  if (tid == 0) samp[0] = 0;
  __syncthreads();

  // point k (k=0..7) of this thread is index k*1024+tid; pair j holds k=2j,2j+1
  f32x2 px[4], py[4], pz[4], dmin[4];
#pragma unroll
  for (int j = 0; j < 4; ++j) {
    int p0 = (2 * j) * 1024 + tid, p1 = (2 * j + 1) * 1024 + tid;
    px[j] = f32x2{xs[p0], xs[p1]};
    py[j] = f32x2{ys[p0], ys[p1]};
    pz[j] = f32x2{zs[p0], zs[p1]};
    dmin[j] = f32x2{1e10f, 1e10f};
  }
  int cur = 0;
  for (int it = 1; it < N_SAMP; ++it) {
    float cx = xs[cur], cy = ys[cur], cz = zs[cur];
    f32x2 cX = {cx, cx}, cY = {cy, cy}, cZ = {cz, cz};
    float bestd = -1.0f; int bestk = 0;
#pragma unroll
    for (int j = 0; j < 4; ++j) {
      // match reference: sub, square, left-assoc add; contraction OFF
      f32x2 dx = px[j] - cX;
      f32x2 dy = py[j] - cY;
      f32x2 dz = pz[j] - cZ;
      f32x2 d = (dx * dx + dy * dy) + dz * dz;
      float m0 = fminf(dmin[j].x, d.x);
      float m1 = fminf(dmin[j].y, d.y);
      dmin[j].x = m0; dmin[j].y = m1;
      if (m0 > bestd) { bestd = m0; bestk = 2 * j; }
      if (m1 > bestd) { bestd = m1; bestk = 2 * j + 1; }
    }
    int bestp = bestk * 1024 + tid;
    unsigned long long key =
        ((unsigned long long)__float_as_uint(bestd) << 32) | (unsigned)(~bestp);
#pragma unroll
    for (int o = 32; o > 0; o >>= 1) {
      unsigned long long other = __shfl_xor(key, o, 64);
      key = (other > key) ? other : key;
    }
    if (lane == 0) red[it & 1][wid] = key;
    __syncthreads();
    const unsigned long long* rr = red[it & 1];
    unsigned long long g = rr[0];
#pragma unroll
    for (int w2 = 1; w2 < 16; ++w2) {
      unsigned long long v = rr[w2];
      g = (v > g) ? v : g;
    }
    cur = (int)(~(unsigned)g);
    if (tid == 0) samp[it] = cur;
  }
  __syncthreads();
  for (int s = tid; s < N_SAMP; s += 1024) {
    int idx = samp[s];
    fps_idx[b * N_SAMP + s] = idx;
    size_t o = ((size_t)b * N_SAMP + s) * 3;
    new_xyz[o] = xs[idx]; new_xyz[o + 1] = ys[idx]; new_xyz[o + 2] = zs[idx];
  }
}

// ---------------------------------------------------------------- kNN
// One wave per query. Per-lane sorted top-16 (packed u64), 16-round
// wave-min merge. d = (qn+pn) - 2*dot, dot as fma chain (Eigen-gemm style).
__global__ __launch_bounds__(256) void knn_kernel(const float* __restrict__ xyz,
                                                  const float* __restrict__ new_xyz,
                                                  int* __restrict__ knn_idx) {
  const int wid = threadIdx.x >> 6, lane = threadIdx.x & 63;
  const int q = blockIdx.x * 4 + wid;
  const int b = q >> 11;
  const float* qp = new_xyz + (size_t)q * 3;
  float q0 = qp[0], q1 = qp[1], q2 = qp[2];
  float qn = __fadd_rn(__fadd_rn(__fmul_rn(q0, q0), __fmul_rn(q1, q1)), __fmul_rn(q2, q2));
  const float* pb = xyz + (size_t)b * N_PTS * 3;
  unsigned long long arr[16];
#pragma unroll
  for (int i = 0; i < 16; ++i) arr[i] = ~0ull;
  for (int p = lane; p < N_PTS; p += 64) {
    float p0 = pb[p * 3 + 0], p1 = pb[p * 3 + 1], p2 = pb[p * 3 + 2];
    float pn = __fadd_rn(__fadd_rn(__fmul_rn(p0, p0), __fmul_rn(p1, p1)), __fmul_rn(p2, p2));
    float dt = fmaf(q2, p2, fmaf(q1, p1, __fmul_rn(q0, p0)));
    float d = __fsub_rn(__fadd_rn(qn, pn), __fmul_rn(2.0f, dt));
    unsigned ub = __float_as_uint(d);
    ub ^= (unsigned)((int)ub >> 31) | 0x80000000u;  // order-preserving map (handles d<0)
    unsigned long long key = ((unsigned long long)ub << 32) | (unsigned)p;
    if (key < arr[15]) {
      unsigned long long curk = key;
#pragma unroll
      for (int j = 0; j < 16; ++j) {
        unsigned long long lo = (curk < arr[j]) ? curk : arr[j];
        unsigned long long hi = (curk < arr[j]) ? arr[j] : curk;
        arr[j] = lo; curk = hi;
      }
    }
  }
  for (int r = 0; r < KNN_K; ++r) {
    unsigned long long m = arr[0];
#pragma unroll
    for (int o = 32; o > 0; o >>= 1) {
      unsigned long long other = __shfl_xor(m, o, 64);
      m = (other < m) ? other : m;
    }
    if (arr[0] == m) {  // unique winner (idx in low bits)
#pragma unroll
      for (int j = 0; j < 15; ++j) arr[j] = arr[j + 1];
      arr[15] = ~0ull;
    }
    if (lane == r) knn_idx[(size_t)q * KNN_K + r] = (int)(m & 0xFFFFFFFFu);
  }
}

// ---------------------------------------------------------------- MLP passes
// PASS 0: mm1 -> stats1.  PASS 1: mm1->BN1->relu->mm2 -> stats2.
// PASS 2: full chain -> BN2 -> relu -> max over K -> out.
// Block = one (b,s): 16 rows (K) x 128 ch; thread (k, cg) owns 8 channels.
template <int PASS>
__global__ __launch_bounds__(256) void mlp_kernel(
    const float* __restrict__ xyz, const float* __restrict__ feat,
    const float* __restrict__ W1, const float* __restrict__ g1v, const float* __restrict__ b1v,
    const float* __restrict__ W2, const float* __restrict__ g2v, const float* __restrict__ b2v,
    const float* __restrict__ new_xyz, const int* __restrict__ knn_idx,
    float* __restrict__ stats1, float* __restrict__ stats2,
    float* __restrict__ out_feat) {
  constexpr int BUFA = (PASS == 0) ? (67 * 128) : (128 * 128);
  constexpr int ZR = (PASS == 0) ? 1 : 16;
  __shared__ __align__(16) float bufA[BUFA];     // W1, then (PASS>=1) W2
  __shared__ float xrow[16][68];
  __shared__ float zS[ZR][132];
  __shared__ float spart[4][16][16];
  __shared__ int nidx[16];
  __shared__ float qv[3];
  const int tid = threadIdx.x;
  const int bs = blockIdx.x;
  const int b = bs >> 11;
  const int lane = tid & 63, w = tid >> 6;
  const int k = tid >> 4, cg = tid & 15;
  const float inv_m = 1.0f / (float)BN_M;

  if (tid < 16) nidx[tid] = knn_idx[(size_t)bs * KNN_K + tid];
  if (tid >= 32 && tid < 35) qv[tid - 32] = new_xyz[(size_t)bs * 3 + (tid - 32)];
  for (int i = tid; i < 67 * 128; i += 256) bufA[i] = W1[i];
  __syncthreads();
  for (int i = tid; i < 16 * 64; i += 256) {
    int kk = i >> 6, c = i & 63;
    xrow[kk][c] = feat[((size_t)b * N_PTS + nidx[kk]) * 64 + c];
  }
  if (tid < 48) {
    int kk = tid / 3, c = tid - kk * 3;
    xrow[kk][64 + c] = __fsub_rn(xyz[((size_t)b * N_PTS + nidx[kk]) * 3 + c], qv[c]);
  }
  __syncthreads();

  float acc[8];
#pragma unroll
  for (int i = 0; i < 8; ++i) acc[i] = 0.f;
  for (int j = 0; j < 67; ++j) {
    float xv = xrow[k][j];
    const float4* wp = reinterpret_cast<const float4*>(&bufA[j * 128 + cg * 8]);
    float4 wa = wp[0], wb = wp[1];
    acc[0] = fmaf(xv, wa.x, acc[0]); acc[1] = fmaf(xv, wa.y, acc[1]);
    acc[2] = fmaf(xv, wa.z, acc[2]); acc[3] = fmaf(xv, wa.w, acc[3]);
    acc[4] = fmaf(xv, wb.x, acc[4]); acc[5] = fmaf(xv, wb.y, acc[5]);
    acc[6] = fmaf(xv, wb.z, acc[6]); acc[7] = fmaf(xv, wb.w, acc[7]);
  }

  if constexpr (PASS == 0) {
    float sq[8];
#pragma unroll
    for (int i = 0; i < 8; ++i) sq[i] = acc[i] * acc[i];
#pragma unroll
    for (int i = 0; i < 8; ++i) {
      acc[i] += __shfl_xor(acc[i], 16, 64); sq[i] += __shfl_xor(sq[i], 16, 64);
      acc[i] += __shfl_xor(acc[i], 32, 64); sq[i] += __shfl_xor(sq[i], 32, 64);
    }
    if (lane < 16) {
#pragma unroll
      for (int i = 0; i < 8; ++i) { spart[w][cg][i] = acc[i]; spart[w][cg][8 + i] = sq[i]; }
    }
    __syncthreads();
    {
      int ch = tid & 127, half = tid >> 7;
      float v = 0.f;
#pragma unroll
      for (int ww = 0; ww < 4; ++ww) v += spart[ww][ch >> 3][half * 8 + (ch & 7)];
      atomicAdd(&stats1[half * 128 + ch], v);
    }
    return;
  } else {
    // BN1 + relu -> zS
#pragma unroll
    for (int i = 0; i < 8; ++i) {
      int ch = cg * 8 + i;
      float mean = stats1[ch] * inv_m;
      float var = stats1[128 + ch] * inv_m - mean * mean;
      float rs = rsqrtf(var + 1e-5f);
      float zz = (acc[i] - mean) * rs * g1v[ch] + b1v[ch];
      zS[k][ch] = fmaxf(zz, 0.f);
    }
    __syncthreads();
    for (int i = tid; i < 128 * 128; i += 256) bufA[i] = W2[i];
    __syncthreads();
    float u[8];
#pragma unroll
    for (int i = 0; i < 8; ++i) u[i] = 0.f;
    for (int j = 0; j < 128; ++j) {
      float zv = zS[k][j];
      const float4* wp = reinterpret_cast<const float4*>(&bufA[j * 128 + cg * 8]);
      float4 wa = wp[0], wb = wp[1];
      u[0] = fmaf(zv, wa.x, u[0]); u[1] = fmaf(zv, wa.y, u[1]);
      u[2] = fmaf(zv, wa.z, u[2]); u[3] = fmaf(zv, wa.w, u[3]);
      u[4] = fmaf(zv, wb.x, u[4]); u[5] = fmaf(zv, wb.y, u[5]);
      u[6] = fmaf(zv, wb.z, u[6]); u[7] = fmaf(zv, wb.w, u[7]);
    }

    if constexpr (PASS == 1) {
      float sq[8];
#pragma unroll
      for (int i = 0; i < 8; ++i) sq[i] = u[i] * u[i];
#pragma unroll
      for (int i = 0; i < 8; ++i) {
        u[i] += __shfl_xor(u[i], 16, 64); sq[i] += __shfl_xor(sq[i], 16, 64);
        u[i] += __shfl_xor(u[i], 32, 64); sq[i] += __shfl_xor(sq[i], 32, 64);
      }
      if (lane < 16) {
#pragma unroll
        for (int i = 0; i < 8; ++i) { spart[w][cg][i] = u[i]; spart[w][cg][8 + i] = sq[i]; }
      }
      __syncthreads();
      {
        int ch = tid & 127, half = tid >> 7;
        float v = 0.f;
#pragma unroll
        for (int ww = 0; ww < 4; ++ww) v += spart[ww][ch >> 3][half * 8 + (ch & 7)];
        atomicAdd(&stats2[half * 128 + ch], v);
      }
      return;
    } else {
      // BN2 + relu + max over K
      float v8[8];
#pragma unroll
      for (int i = 0; i < 8; ++i) {
        int ch = cg * 8 + i;
        float mean = stats2[ch] * inv_m;
        float var = stats2[128 + ch] * inv_m - mean * mean;
        float rs = rsqrtf(var + 1e-5f);
        float vv = (u[i] - mean) * rs * g2v[ch] + b2v[ch];
        v8[i] = fmaxf(vv, 0.f);
      }
#pragma unroll
      for (int i = 0; i < 8; ++i) {
        v8[i] = fmaxf(v8[i], __shfl_xor(v8[i], 16, 64));
        v8[i] = fmaxf(v8[i], __shfl_xor(v8[i], 32, 64));
      }
      if (lane < 16) {
#pragma unroll
        for (int i = 0; i < 8; ++i) spart[w][cg][i] = v8[i];
      }
      __syncthreads();
      if (tid < 128) {
        int ch = tid;
        float m = spart[0][ch >> 3][ch & 7];
#pragma unroll
        for (int ww = 1; ww < 4; ++ww) m = fmaxf(m, spart[ww][ch >> 3][ch & 7]);
        out_feat[(size_t)bs * 128 + ch] = m;
      }
    }
  }
}

extern "C" void kernel_launch(void* const* d_in, const int* in_sizes, int n_in,
                              void* d_out, int out_size, void* d_ws, size_t ws_size,
                              hipStream_t stream) {
  const float* xyz  = (const float*)d_in[0];
  const float* feat = (const float*)d_in[1];
  const float* W1   = (const float*)d_in[2];
  const float* g1   = (const float*)d_in[3];
  const float* b1   = (const float*)d_in[4];
  const float* W2   = (const float*)d_in[5];
  const float* g2   = (const float*)d_in[6];
  const float* b2   = (const float*)d_in[7];
  float* out = (float*)d_out;
  float* new_xyz = out;                              // [4,2048,3]
  float* out_feat = out + NBATCH * N_SAMP * 3;       // [4,2048,128]

  int* fps_i = (int*)d_ws;                           // [4,2048]
  int* knn_i = fps_i + NBATCH * N_SAMP;              // [4,2048,16]
  float* stats1 = (float*)(knn_i + NBATCH * N_SAMP * KNN_K);  // [256]
  float* stats2 = stats1 + 256;                      // [256]

  hipMemsetAsync(stats1, 0, 512 * sizeof(float), stream);
  hipLaunchKernelGGL(fps_kernel, dim3(NBATCH), dim3(1024), 0, stream, xyz, fps_i, new_xyz);
  hipLaunchKernelGGL(knn_kernel, dim3((NBATCH * N_SAMP) / 4), dim3(256), 0, stream,
                     xyz, new_xyz, knn_i);
  hipLaunchKernelGGL((mlp_kernel<0>), dim3(NBATCH * N_SAMP), dim3(256), 0, stream,
                     xyz, feat, W1, g1, b1, W2, g2, b2, new_xyz, knn_i, stats1, stats2, out_feat);
  hipLaunchKernelGGL((mlp_kernel<1>), dim3(NBATCH * N_SAMP), dim3(256), 0, stream,
                     xyz, feat, W1, g1, b1, W2, g2, b2, new_xyz, knn_i, stats1, stats2, out_feat);
  hipLaunchKernelGGL((mlp_kernel<2>), dim3(NBATCH * N_SAMP), dim3(256), 0, stream,
                     xyz, feat, W1, g1, b1, W2, g2, b2, new_xyz, knn_i, stats1, stats2, out_feat);
}

// Round 3
// 3461.198 us; speedup vs baseline: 1.1468x; 1.1468x over previous
//
#include <hip/hip_runtime.h>
#include <hip/hip_bf16.h>

#define N_PTS 8192
#define N_SAMP 2048
#define KNN_K 16
#define NBATCH 4
#define BN_M (NBATCH * N_SAMP * KNN_K)  // 131072

typedef float f32x2 __attribute__((ext_vector_type(2)));

// u64 max with DPP-shuffled partner. CTRL compile-time: quad_perm/row_ror are
// direction-free (full-lane valid); row_bcast15/31 use rocPRIM row masks.
template <int CTRL, int RM>
__device__ __forceinline__ unsigned long long kmax_dpp(unsigned long long k) {
  int lo = (int)(unsigned)k, hi = (int)(unsigned)(k >> 32);
  int lo2 = __builtin_amdgcn_update_dpp(lo, lo, CTRL, RM, 0xF, false);
  int hi2 = __builtin_amdgcn_update_dpp(hi, hi, CTRL, RM, 0xF, false);
  unsigned long long o = ((unsigned long long)(unsigned)hi2 << 32) | (unsigned)lo2;
  return (o > k) ? o : k;
}

// ---------------------------------------------------------------- FPS
// One block per batch. xyz packed float4 in LDS; each thread's 8 points in
// registers (4x f32x2). All cross-lane reduction via DPP (VALU pipe) — the
// R1 profile showed the DS pipe (shfl butterflies + LDS reads) was the
// bottleneck. Key = (f32bits(dmin)<<32)|(0x3FFF-idx): max => farthest,
// ties => smallest index (matches jnp.argmax).
__global__ __launch_bounds__(1024) void fps_kernel(const float* __restrict__ xyz,
                                                   int* __restrict__ fps_idx,
                                                   float* __restrict__ new_xyz) {
#pragma clang fp contract(off)
  __shared__ __align__(16) float xyzw[N_PTS * 4];
  __shared__ int samp[N_SAMP];
  __shared__ unsigned long long red[2][16];
  const int b = blockIdx.x;
  const int tid = threadIdx.x;
  const int lane = tid & 63;
  const int wid = tid >> 6;
  const float* base = xyz + (size_t)b * N_PTS * 3;
  for (int i = tid; i < N_PTS * 3; i += 1024) {
    float v = base[i];
    int p = i / 3, c = i - p * 3;
    xyzw[p * 4 + c] = v;
  }
  if (tid == 0) samp[0] = 0;
  __syncthreads();

  // point k (k=0..7) of this thread is index k*1024+tid; pair j holds k=2j,2j+1
  f32x2 px[4], py[4], pz[4], dmin[4];
#pragma unroll
  for (int j = 0; j < 4; ++j) {
    int p0 = (2 * j) * 1024 + tid, p1 = p0 + 1024;
    const float4 a = *reinterpret_cast<const float4*>(&xyzw[p0 * 4]);
    const float4 c = *reinterpret_cast<const float4*>(&xyzw[p1 * 4]);
    px[j] = f32x2{a.x, c.x};
    py[j] = f32x2{a.y, c.y};
    pz[j] = f32x2{a.z, c.z};
    dmin[j] = f32x2{1e10f, 1e10f};
  }
  int cur = 0;
  for (int it = 1; it < N_SAMP; ++it) {
    const float4 c4 = *reinterpret_cast<const float4*>(&xyzw[cur * 4]);
    f32x2 cX = {c4.x, c4.x}, cY = {c4.y, c4.y}, cZ = {c4.z, c4.z};
#pragma unroll
    for (int j = 0; j < 4; ++j) {
      // match reference: sub, square, left-assoc add; contraction OFF
      f32x2 dx = px[j] - cX;
      f32x2 dy = py[j] - cY;
      f32x2 dz = pz[j] - cZ;
      f32x2 s0 = dx * dx;
      f32x2 s1 = dy * dy;
      f32x2 s01 = s0 + s1;
      f32x2 s2 = dz * dz;
      f32x2 d = s01 + s2;
      dmin[j].x = fminf(dmin[j].x, d.x);
      dmin[j].y = fminf(dmin[j].y, d.y);
    }
    // thread-local max + smallest-k tie rule (deferred argmax)
    f32x2 m01 = {fmaxf(dmin[0].x, dmin[1].x), fmaxf(dmin[0].y, dmin[1].y)};
    f32x2 m23 = {fmaxf(dmin[2].x, dmin[3].x), fmaxf(dmin[2].y, dmin[3].y)};
    f32x2 mm = {fmaxf(m01.x, m23.x), fmaxf(m01.y, m23.y)};
    float bestd = fmaxf(mm.x, mm.y);
    int bestk;
    bestk = (dmin[3].y == bestd) ? 7 : 0;
    bestk = (dmin[3].x == bestd) ? 6 : bestk;
    bestk = (dmin[2].y == bestd) ? 5 : bestk;
    bestk = (dmin[2].x == bestd) ? 4 : bestk;
    bestk = (dmin[1].y == bestd) ? 3 : bestk;
    bestk = (dmin[1].x == bestd) ? 2 : bestk;
    bestk = (dmin[0].y == bestd) ? 1 : bestk;
    bestk = (dmin[0].x == bestd) ? 0 : bestk;
    int bestp = bestk * 1024 + tid;
    unsigned long long key =
        ((unsigned long long)__float_as_uint(bestd) << 32) | (unsigned)(0x3FFF - bestp);
    // full-wave u64 max, VALU-only (DPP): xor1, xor2, ror4, ror8, bcast15, bcast31
    key = kmax_dpp<0xB1, 0xF>(key);
    key = kmax_dpp<0x4E, 0xF>(key);
    key = kmax_dpp<0x124, 0xF>(key);
    key = kmax_dpp<0x128, 0xF>(key);
    key = kmax_dpp<0x142, 0xA>(key);
    key = kmax_dpp<0x143, 0xC>(key);
    unsigned glo = (unsigned)__builtin_amdgcn_readlane((int)(unsigned)key, 63);
    unsigned ghi = (unsigned)__builtin_amdgcn_readlane((int)(unsigned)(key >> 32), 63);
    if (lane == 0)
      red[it & 1][wid] = ((unsigned long long)ghi << 32) | glo;
    __syncthreads();
    // stage 2: 16 wave keys -> global max; rows replicated so 4 direction-free
    // DPP levels give every lane the answer. 1 DS read, no extra barrier.
    unsigned long long k2 = red[it & 1][lane & 15];
    k2 = kmax_dpp<0xB1, 0xF>(k2);
    k2 = kmax_dpp<0x4E, 0xF>(k2);
    k2 = kmax_dpp<0x124, 0xF>(k2);
    k2 = kmax_dpp<0x128, 0xF>(k2);
    cur = 0x3FFF - (int)(unsigned)k2;
    if (tid == 0) samp[it] = cur;
  }
  __syncthreads();
  for (int s = tid; s < N_SAMP; s += 1024) {
    int idx = samp[s];
    fps_idx[b * N_SAMP + s] = idx;
    size_t o = ((size_t)b * N_SAMP + s) * 3;
    new_xyz[o] = xyzw[idx * 4 + 0];
    new_xyz[o + 1] = xyzw[idx * 4 + 1];
    new_xyz[o + 2] = xyzw[idx * 4 + 2];
  }
}

// ---------------------------------------------------------------- kNN
// One wave per query. Per-lane sorted top-16 (packed u64), 16-round
// wave-min merge. d = (qn+pn) - 2*dot, dot as fma chain (Eigen-gemm style).
__global__ __launch_bounds__(256) void knn_kernel(const float* __restrict__ xyz,
                                                  const float* __restrict__ new_xyz,
                                                  int* __restrict__ knn_idx) {
  const int wid = threadIdx.x >> 6, lane = threadIdx.x & 63;
  const int q = blockIdx.x * 4 + wid;
  const int b = q >> 11;
  const float* qp = new_xyz + (size_t)q * 3;
  float q0 = qp[0], q1 = qp[1], q2 = qp[2];
  float qn = __fadd_rn(__fadd_rn(__fmul_rn(q0, q0), __fmul_rn(q1, q1)), __fmul_rn(q2, q2));
  const float* pb = xyz + (size_t)b * N_PTS * 3;
  unsigned long long arr[16];
#pragma unroll
  for (int i = 0; i < 16; ++i) arr[i] = ~0ull;
  for (int p = lane; p < N_PTS; p += 64) {
    float p0 = pb[p * 3 + 0], p1 = pb[p * 3 + 1], p2 = pb[p * 3 + 2];
    float pn = __fadd_rn(__fadd_rn(__fmul_rn(p0, p0), __fmul_rn(p1, p1)), __fmul_rn(p2, p2));
    float dt = fmaf(q2, p2, fmaf(q1, p1, __fmul_rn(q0, p0)));
    float d = __fsub_rn(__fadd_rn(qn, pn), __fmul_rn(2.0f, dt));
    unsigned ub = __float_as_uint(d);
    ub ^= (unsigned)((int)ub >> 31) | 0x80000000u;  // order-preserving map (handles d<0)
    unsigned long long key = ((unsigned long long)ub << 32) | (unsigned)p;
    if (key < arr[15]) {
      unsigned long long curk = key;
#pragma unroll
      for (int j = 0; j < 16; ++j) {
        unsigned long long lo = (curk < arr[j]) ? curk : arr[j];
        unsigned long long hi = (curk < arr[j]) ? arr[j] : curk;
        arr[j] = lo; curk = hi;
      }
    }
  }
  for (int r = 0; r < KNN_K; ++r) {
    unsigned long long m = arr[0];
#pragma unroll
    for (int o = 32; o > 0; o >>= 1) {
      unsigned long long other = __shfl_xor(m, o, 64);
      m = (other < m) ? other : m;
    }
    if (arr[0] == m) {  // unique winner (idx in low bits)
#pragma unroll
      for (int j = 0; j < 15; ++j) arr[j] = arr[j + 1];
      arr[15] = ~0ull;
    }
    if (lane == r) knn_idx[(size_t)q * KNN_K + r] = (int)(m & 0xFFFFFFFFu);
  }
}

// ---------------------------------------------------------------- MLP passes
// PASS 0: mm1 -> stats1.  PASS 1: mm1->BN1->relu->mm2 -> stats2.
// PASS 2: full chain -> BN2 -> relu -> max over K -> out.
// Block = one (b,s): 16 rows (K) x 128 ch; thread (k, cg) owns 8 channels.
template <int PASS>
__global__ __launch_bounds__(256) void mlp_kernel(
    const float* __restrict__ xyz, const float* __restrict__ feat,
    const float* __restrict__ W1, const float* __restrict__ g1v, const float* __restrict__ b1v,
    const float* __restrict__ W2, const float* __restrict__ g2v, const float* __restrict__ b2v,
    const float* __restrict__ new_xyz, const int* __restrict__ knn_idx,
    float* __restrict__ stats1, float* __restrict__ stats2,
    float* __restrict__ out_feat) {
  constexpr int BUFA = (PASS == 0) ? (67 * 128) : (128 * 128);
  constexpr int ZR = (PASS == 0) ? 1 : 16;
  __shared__ __align__(16) float bufA[BUFA];     // W1, then (PASS>=1) W2
  __shared__ float xrow[16][68];
  __shared__ float zS[ZR][132];
  __shared__ float spart[4][16][16];
  __shared__ int nidx[16];
  __shared__ float qv[3];
  const int tid = threadIdx.x;
  const int bs = blockIdx.x;
  const int b = bs >> 11;
  const int lane = tid & 63, w = tid >> 6;
  const int k = tid >> 4, cg = tid & 15;
  const float inv_m = 1.0f / (float)BN_M;

  if (tid < 16) nidx[tid] = knn_idx[(size_t)bs * KNN_K + tid];
  if (tid >= 32 && tid < 35) qv[tid - 32] = new_xyz[(size_t)bs * 3 + (tid - 32)];
  for (int i = tid; i < 67 * 128; i += 256) bufA[i] = W1[i];
  __syncthreads();
  for (int i = tid; i < 16 * 64; i += 256) {
    int kk = i >> 6, c = i & 63;
    xrow[kk][c] = feat[((size_t)b * N_PTS + nidx[kk]) * 64 + c];
  }
  if (tid < 48) {
    int kk = tid / 3, c = tid - kk * 3;
    xrow[kk][64 + c] = __fsub_rn(xyz[((size_t)b * N_PTS + nidx[kk]) * 3 + c], qv[c]);
  }
  __syncthreads();

  float acc[8];
#pragma unroll
  for (int i = 0; i < 8; ++i) acc[i] = 0.f;
  for (int j = 0; j < 67; ++j) {
    float xv = xrow[k][j];
    const float4* wp = reinterpret_cast<const float4*>(&bufA[j * 128 + cg * 8]);
    float4 wa = wp[0], wb = wp[1];
    acc[0] = fmaf(xv, wa.x, acc[0]); acc[1] = fmaf(xv, wa.y, acc[1]);
    acc[2] = fmaf(xv, wa.z, acc[2]); acc[3] = fmaf(xv, wa.w, acc[3]);
    acc[4] = fmaf(xv, wb.x, acc[4]); acc[5] = fmaf(xv, wb.y, acc[5]);
    acc[6] = fmaf(xv, wb.z, acc[6]); acc[7] = fmaf(xv, wb.w, acc[7]);
  }

  if constexpr (PASS == 0) {
    float sq[8];
#pragma unroll
    for (int i = 0; i < 8; ++i) sq[i] = acc[i] * acc[i];
#pragma unroll
    for (int i = 0; i < 8; ++i) {
      acc[i] += __shfl_xor(acc[i], 16, 64); sq[i] += __shfl_xor(sq[i], 16, 64);
      acc[i] += __shfl_xor(acc[i], 32, 64); sq[i] += __shfl_xor(sq[i], 32, 64);
    }
    if (lane < 16) {
#pragma unroll
      for (int i = 0; i < 8; ++i) { spart[w][cg][i] = acc[i]; spart[w][cg][8 + i] = sq[i]; }
    }
    __syncthreads();
    {
      int ch = tid & 127, half = tid >> 7;
      float v = 0.f;
#pragma unroll
      for (int ww = 0; ww < 4; ++ww) v += spart[ww][ch >> 3][half * 8 + (ch & 7)];
      atomicAdd(&stats1[half * 128 + ch], v);
    }
    return;
  } else {
    // BN1 + relu -> zS
#pragma unroll
    for (int i = 0; i < 8; ++i) {
      int ch = cg * 8 + i;
      float mean = stats1[ch] * inv_m;
      float var = stats1[128 + ch] * inv_m - mean * mean;
      float rs = rsqrtf(var + 1e-5f);
      float zz = (acc[i] - mean) * rs * g1v[ch] + b1v[ch];
      zS[k][ch] = fmaxf(zz, 0.f);
    }
    __syncthreads();
    for (int i = tid; i < 128 * 128; i += 256) bufA[i] = W2[i];
    __syncthreads();
    float u[8];
#pragma unroll
    for (int i = 0; i < 8; ++i) u[i] = 0.f;
    for (int j = 0; j < 128; ++j) {
      float zv = zS[k][j];
      const float4* wp = reinterpret_cast<const float4*>(&bufA[j * 128 + cg * 8]);
      float4 wa = wp[0], wb = wp[1];
      u[0] = fmaf(zv, wa.x, u[0]); u[1] = fmaf(zv, wa.y, u[1]);
      u[2] = fmaf(zv, wa.z, u[2]); u[3] = fmaf(zv, wa.w, u[3]);
      u[4] = fmaf(zv, wb.x, u[4]); u[5] = fmaf(zv, wb.y, u[5]);
      u[6] = fmaf(zv, wb.z, u[6]); u[7] = fmaf(zv, wb.w, u[7]);
    }

    if constexpr (PASS == 1) {
      float sq[8];
#pragma unroll
      for (int i = 0; i < 8; ++i) sq[i] = u[i] * u[i];
#pragma unroll
      for (int i = 0; i < 8; ++i) {
        u[i] += __shfl_xor(u[i], 16, 64); sq[i] += __shfl_xor(sq[i], 16, 64);
        u[i] += __shfl_xor(u[i], 32, 64); sq[i] += __shfl_xor(sq[i], 32, 64);
      }
      if (lane < 16) {
#pragma unroll
        for (int i = 0; i < 8; ++i) { spart[w][cg][i] = u[i]; spart[w][cg][8 + i] = sq[i]; }
      }
      __syncthreads();
      {
        int ch = tid & 127, half = tid >> 7;
        float v = 0.f;
#pragma unroll
        for (int ww = 0; ww < 4; ++ww) v += spart[ww][ch >> 3][half * 8 + (ch & 7)];
        atomicAdd(&stats2[half * 128 + ch], v);
      }
      return;
    } else {
      // BN2 + relu + max over K
      float v8[8];
#pragma unroll
      for (int i = 0; i < 8; ++i) {
        int ch = cg * 8 + i;
        float mean = stats2[ch] * inv_m;
        float var = stats2[128 + ch] * inv_m - mean * mean;
        float rs = rsqrtf(var + 1e-5f);
        float vv = (u[i] - mean) * rs * g2v[ch] + b2v[ch];
        v8[i] = fmaxf(vv, 0.f);
      }
#pragma unroll
      for (int i = 0; i < 8; ++i) {
        v8[i] = fmaxf(v8[i], __shfl_xor(v8[i], 16, 64));
        v8[i] = fmaxf(v8[i], __shfl_xor(v8[i], 32, 64));
      }
      if (lane < 16) {
#pragma unroll
        for (int i = 0; i < 8; ++i) spart[w][cg][i] = v8[i];
      }
      __syncthreads();
      if (tid < 128) {
        int ch = tid;
        float m = spart[0][ch >> 3][ch & 7];
#pragma unroll
        for (int ww = 1; ww < 4; ++ww) m = fmaxf(m, spart[ww][ch >> 3][ch & 7]);
        out_feat[(size_t)bs * 128 + ch] = m;
      }
    }
  }
}

extern "C" void kernel_launch(void* const* d_in, const int* in_sizes, int n_in,
                              void* d_out, int out_size, void* d_ws, size_t ws_size,
                              hipStream_t stream) {
  const float* xyz  = (const float*)d_in[0];
  const float* feat = (const float*)d_in[1];
  const float* W1   = (const float*)d_in[2];
  const float* g1   = (const float*)d_in[3];
  const float* b1   = (const float*)d_in[4];
  const float* W2   = (const float*)d_in[5];
  const float* g2   = (const float*)d_in[6];
  const float* b2   = (const float*)d_in[7];
  float* out = (float*)d_out;
  float* new_xyz = out;                              // [4,2048,3]
  float* out_feat = out + NBATCH * N_SAMP * 3;       // [4,2048,128]

  int* fps_i = (int*)d_ws;                           // [4,2048]
  int* knn_i = fps_i + NBATCH * N_SAMP;              // [4,2048,16]
  float* stats1 = (float*)(knn_i + NBATCH * N_SAMP * KNN_K);  // [256]
  float* stats2 = stats1 + 256;                      // [256]

  hipMemsetAsync(stats1, 0, 512 * sizeof(float), stream);
  hipLaunchKernelGGL(fps_kernel, dim3(NBATCH), dim3(1024), 0, stream, xyz, fps_i, new_xyz);
  hipLaunchKernelGGL(knn_kernel, dim3((NBATCH * N_SAMP) / 4), dim3(256), 0, stream,
                     xyz, new_xyz, knn_i);
  hipLaunchKernelGGL((mlp_kernel<0>), dim3(NBATCH * N_SAMP), dim3(256), 0, stream,
                     xyz, feat, W1, g1, b1, W2, g2, b2, new_xyz, knn_i, stats1, stats2, out_feat);
  hipLaunchKernelGGL((mlp_kernel<1>), dim3(NBATCH * N_SAMP), dim3(256), 0, stream,
                     xyz, feat, W1, g1, b1, W2, g2, b2, new_xyz, knn_i, stats1, stats2, out_feat);
  hipLaunchKernelGGL((mlp_kernel<2>), dim3(NBATCH * N_SAMP), dim3(256), 0, stream,
                     xyz, feat, W1, g1, b1, W2, g2, b2, new_xyz, knn_i, stats1, stats2, out_feat);
}

// Round 4
// 3037.835 us; speedup vs baseline: 1.3066x; 1.1394x over previous
//
#include <hip/hip_runtime.h>
#include <hip/hip_bf16.h>

#define N_PTS 8192
#define N_SAMP 2048
#define KNN_K 16
#define NBATCH 4
#define BN_M (NBATCH * N_SAMP * KNN_K)  // 131072

typedef float f32x2 __attribute__((ext_vector_type(2)));

// u32 max with DPP-shuffled partner (VALU pipe only). bound_ctrl=false +
// old=src: lanes with invalid sources keep their own value (max(v,v)=v, safe).
template <int CTRL, int RM>
__device__ __forceinline__ unsigned umax_dpp(unsigned v) {
  unsigned o = (unsigned)__builtin_amdgcn_update_dpp((int)v, (int)v, CTRL, RM, 0xF, false);
  return (o > v) ? o : v;
}

// ---------------------------------------------------------------- FPS
// One block per batch, 512 threads, 16 pts/thread in registers (8x f32x2).
// Per iter: distance+min (pk f32, contract off, bit-exact vs reference) ->
// local max -> wave u32-bit max via DPP (dmin>=0 so f32 order == u32 bit
// order) -> lane63 writes wave max -> barrier -> all waves combine 8 wave
// maxima (1 LDS read + 3 DPP levels) -> ONLY threads whose local max equals
// the global max (~1 of 512) run an exec-masked descending equality scan and
// LDS atomicMin their lowest matching point index (ties -> lowest index =
// jnp.argmax first-occurrence) -> barrier. Winner index read next iter from
// parity-double-buffered winslot.
__global__ __launch_bounds__(512) void fps_kernel(const float* __restrict__ xyz,
                                                  int* __restrict__ fps_idx,
                                                  float* __restrict__ new_xyz) {
#pragma clang fp contract(off)
  __shared__ __align__(16) float xyzw[N_PTS * 4];
  __shared__ int samp[N_SAMP];
  __shared__ unsigned redbuf[8];
  __shared__ unsigned winslot[2];
  const int b = blockIdx.x;
  const int tid = threadIdx.x;
  const int lane = tid & 63;
  const int wid = tid >> 6;
  const float* base = xyz + (size_t)b * N_PTS * 3;
  for (int i = tid; i < N_PTS * 3; i += 512) {
    float v = base[i];
    int p = i / 3, c = i - p * 3;
    xyzw[p * 4 + c] = v;
  }
  for (int i = tid; i < N_PTS; i += 512) xyzw[i * 4 + 3] = 0.f;
  if (tid == 0) { winslot[0] = 0u; winslot[1] = 0xFFFFFFFFu; }
  __syncthreads();

  // point k (k=0..15) of this thread is index k*512+tid; pair j holds k=2j,2j+1
  f32x2 px[8], py[8], pz[8], dmin[8];
#pragma unroll
  for (int j = 0; j < 8; ++j) {
    int p0 = (2 * j) * 512 + tid, p1 = p0 + 512;
    const float4 a = *reinterpret_cast<const float4*>(&xyzw[p0 * 4]);
    const float4 c = *reinterpret_cast<const float4*>(&xyzw[p1 * 4]);
    px[j] = f32x2{a.x, c.x};
    py[j] = f32x2{a.y, c.y};
    pz[j] = f32x2{a.z, c.z};
    dmin[j] = f32x2{1e10f, 1e10f};
  }
  for (int it = 1; it < N_SAMP; ++it) {
    const int p = it & 1;
    const unsigned cur = winslot[p ^ 1];
    if (tid == 0) samp[it - 1] = (int)cur;
    const float4 c4 = *reinterpret_cast<const float4*>(&xyzw[cur * 4]);
    f32x2 cX = {c4.x, c4.x}, cY = {c4.y, c4.y}, cZ = {c4.z, c4.z};
#pragma unroll
    for (int j = 0; j < 8; ++j) {
      // match reference: sub, square, left-assoc add; contraction OFF
      f32x2 dx = px[j] - cX;
      f32x2 dy = py[j] - cY;
      f32x2 dz = pz[j] - cZ;
      f32x2 s01 = dx * dx + dy * dy;
      f32x2 d = s01 + dz * dz;
      dmin[j].x = fminf(dmin[j].x, d.x);
      dmin[j].y = fminf(dmin[j].y, d.y);
    }
    // thread-local max (value only; index recovered by exception below)
    f32x2 m0 = {fmaxf(dmin[0].x, dmin[1].x), fmaxf(dmin[0].y, dmin[1].y)};
    f32x2 m1 = {fmaxf(dmin[2].x, dmin[3].x), fmaxf(dmin[2].y, dmin[3].y)};
    f32x2 m2 = {fmaxf(dmin[4].x, dmin[5].x), fmaxf(dmin[4].y, dmin[5].y)};
    f32x2 m3 = {fmaxf(dmin[6].x, dmin[7].x), fmaxf(dmin[6].y, dmin[7].y)};
    f32x2 n0 = {fmaxf(m0.x, m1.x), fmaxf(m0.y, m1.y)};
    f32x2 n1 = {fmaxf(m2.x, m3.x), fmaxf(m2.y, m3.y)};
    f32x2 nn = {fmaxf(n0.x, n1.x), fmaxf(n0.y, n1.y)};
    const unsigned bd = __float_as_uint(fmaxf(nn.x, nn.y));
    // wave max (u32 bits): xor1, xor2, ror4, ror8, bcast15, bcast31 -> lane63
    unsigned r = bd;
    r = umax_dpp<0xB1, 0xF>(r);
    r = umax_dpp<0x4E, 0xF>(r);
    r = umax_dpp<0x124, 0xF>(r);
    r = umax_dpp<0x128, 0xF>(r);
    r = umax_dpp<0x142, 0xA>(r);
    r = umax_dpp<0x143, 0xC>(r);
    if (lane == 63) redbuf[wid] = r;
    __syncthreads();
    if (tid == 0) winslot[p ^ 1] = 0xFFFFFFFFu;  // reset for iter it+1's atomicMin
    // combine 8 wave maxima: period-8 pattern; xor1+xor2+ror4 covers all 8
    unsigned g = redbuf[lane & 7];
    g = umax_dpp<0xB1, 0xF>(g);
    g = umax_dpp<0x4E, 0xF>(g);
    g = umax_dpp<0x124, 0xF>(g);
    if (bd == g) {  // rare: this thread holds the global max
      unsigned cand = 0xFFFFFFFFu;
#pragma unroll
      for (int j = 7; j >= 0; --j) {  // descending => lowest idx wins
        if (__float_as_uint(dmin[j].y) == g) cand = (unsigned)((2 * j + 1) * 512 + tid);
        if (__float_as_uint(dmin[j].x) == g) cand = (unsigned)((2 * j) * 512 + tid);
      }
      atomicMin(&winslot[p], cand);
    }
    __syncthreads();
  }
  if (tid == 0) samp[N_SAMP - 1] = (int)winslot[(N_SAMP - 1) & 1];
  __syncthreads();
  for (int s = tid; s < N_SAMP; s += 512) {
    int idx = samp[s];
    fps_idx[b * N_SAMP + s] = idx;
    size_t o = ((size_t)b * N_SAMP + s) * 3;
    new_xyz[o] = xyzw[idx * 4 + 0];
    new_xyz[o + 1] = xyzw[idx * 4 + 1];
    new_xyz[o + 2] = xyzw[idx * 4 + 2];
  }
}

// ---------------------------------------------------------------- kNN
// One wave per query. Per-lane sorted top-16 (packed u64), 16-round
// wave-min merge. d = (qn+pn) - 2*dot, dot as fma chain (Eigen-gemm style).
__global__ __launch_bounds__(256) void knn_kernel(const float* __restrict__ xyz,
                                                  const float* __restrict__ new_xyz,
                                                  int* __restrict__ knn_idx) {
  const int wid = threadIdx.x >> 6, lane = threadIdx.x & 63;
  const int q = blockIdx.x * 4 + wid;
  const int b = q >> 11;
  const float* qp = new_xyz + (size_t)q * 3;
  float q0 = qp[0], q1 = qp[1], q2 = qp[2];
  float qn = __fadd_rn(__fadd_rn(__fmul_rn(q0, q0), __fmul_rn(q1, q1)), __fmul_rn(q2, q2));
  const float* pb = xyz + (size_t)b * N_PTS * 3;
  unsigned long long arr[16];
#pragma unroll
  for (int i = 0; i < 16; ++i) arr[i] = ~0ull;
  for (int p = lane; p < N_PTS; p += 64) {
    float p0 = pb[p * 3 + 0], p1 = pb[p * 3 + 1], p2 = pb[p * 3 + 2];
    float pn = __fadd_rn(__fadd_rn(__fmul_rn(p0, p0), __fmul_rn(p1, p1)), __fmul_rn(p2, p2));
    float dt = fmaf(q2, p2, fmaf(q1, p1, __fmul_rn(q0, p0)));
    float d = __fsub_rn(__fadd_rn(qn, pn), __fmul_rn(2.0f, dt));
    unsigned ub = __float_as_uint(d);
    ub ^= (unsigned)((int)ub >> 31) | 0x80000000u;  // order-preserving map (handles d<0)
    unsigned long long key = ((unsigned long long)ub << 32) | (unsigned)p;
    if (key < arr[15]) {
      unsigned long long curk = key;
#pragma unroll
      for (int j = 0; j < 16; ++j) {
        unsigned long long lo = (curk < arr[j]) ? curk : arr[j];
        unsigned long long hi = (curk < arr[j]) ? arr[j] : curk;
        arr[j] = lo; curk = hi;
      }
    }
  }
  for (int r = 0; r < KNN_K; ++r) {
    unsigned long long m = arr[0];
#pragma unroll
    for (int o = 32; o > 0; o >>= 1) {
      unsigned long long other = __shfl_xor(m, o, 64);
      m = (other < m) ? other : m;
    }
    if (arr[0] == m) {  // unique winner (idx in low bits)
#pragma unroll
      for (int j = 0; j < 15; ++j) arr[j] = arr[j + 1];
      arr[15] = ~0ull;
    }
    if (lane == r) knn_idx[(size_t)q * KNN_K + r] = (int)(m & 0xFFFFFFFFu);
  }
}

// ---------------------------------------------------------------- MLP passes
// PASS 0: mm1 -> stats1.  PASS 1: mm1->BN1->relu->mm2 -> stats2.
// PASS 2: full chain -> BN2 -> relu -> max over K -> out.
// Block = one (b,s): 16 rows (K) x 128 ch; thread (k, cg) owns 8 channels.
template <int PASS>
__global__ __launch_bounds__(256) void mlp_kernel(
    const float* __restrict__ xyz, const float* __restrict__ feat,
    const float* __restrict__ W1, const float* __restrict__ g1v, const float* __restrict__ b1v,
    const float* __restrict__ W2, const float* __restrict__ g2v, const float* __restrict__ b2v,
    const float* __restrict__ new_xyz, const int* __restrict__ knn_idx,
    float* __restrict__ stats1, float* __restrict__ stats2,
    float* __restrict__ out_feat) {
  constexpr int BUFA = (PASS == 0) ? (67 * 128) : (128 * 128);
  constexpr int ZR = (PASS == 0) ? 1 : 16;
  __shared__ __align__(16) float bufA[BUFA];     // W1, then (PASS>=1) W2
  __shared__ float xrow[16][68];
  __shared__ float zS[ZR][132];
  __shared__ float spart[4][16][16];
  __shared__ int nidx[16];
  __shared__ float qv[3];
  const int tid = threadIdx.x;
  const int bs = blockIdx.x;
  const int b = bs >> 11;
  const int lane = tid & 63, w = tid >> 6;
  const int k = tid >> 4, cg = tid & 15;
  const float inv_m = 1.0f / (float)BN_M;

  if (tid < 16) nidx[tid] = knn_idx[(size_t)bs * KNN_K + tid];
  if (tid >= 32 && tid < 35) qv[tid - 32] = new_xyz[(size_t)bs * 3 + (tid - 32)];
  for (int i = tid; i < 67 * 128; i += 256) bufA[i] = W1[i];
  __syncthreads();
  for (int i = tid; i < 16 * 64; i += 256) {
    int kk = i >> 6, c = i & 63;
    xrow[kk][c] = feat[((size_t)b * N_PTS + nidx[kk]) * 64 + c];
  }
  if (tid < 48) {
    int kk = tid / 3, c = tid - kk * 3;
    xrow[kk][64 + c] = __fsub_rn(xyz[((size_t)b * N_PTS + nidx[kk]) * 3 + c], qv[c]);
  }
  __syncthreads();

  float acc[8];
#pragma unroll
  for (int i = 0; i < 8; ++i) acc[i] = 0.f;
  for (int j = 0; j < 67; ++j) {
    float xv = xrow[k][j];
    const float4* wp = reinterpret_cast<const float4*>(&bufA[j * 128 + cg * 8]);
    float4 wa = wp[0], wb = wp[1];
    acc[0] = fmaf(xv, wa.x, acc[0]); acc[1] = fmaf(xv, wa.y, acc[1]);
    acc[2] = fmaf(xv, wa.z, acc[2]); acc[3] = fmaf(xv, wa.w, acc[3]);
    acc[4] = fmaf(xv, wb.x, acc[4]); acc[5] = fmaf(xv, wb.y, acc[5]);
    acc[6] = fmaf(xv, wb.z, acc[6]); acc[7] = fmaf(xv, wb.w, acc[7]);
  }

  if constexpr (PASS == 0) {
    float sq[8];
#pragma unroll
    for (int i = 0; i < 8; ++i) sq[i] = acc[i] * acc[i];
#pragma unroll
    for (int i = 0; i < 8; ++i) {
      acc[i] += __shfl_xor(acc[i], 16, 64); sq[i] += __shfl_xor(sq[i], 16, 64);
      acc[i] += __shfl_xor(acc[i], 32, 64); sq[i] += __shfl_xor(sq[i], 32, 64);
    }
    if (lane < 16) {
#pragma unroll
      for (int i = 0; i < 8; ++i) { spart[w][cg][i] = acc[i]; spart[w][cg][8 + i] = sq[i]; }
    }
    __syncthreads();
    {
      int ch = tid & 127, half = tid >> 7;
      float v = 0.f;
#pragma unroll
      for (int ww = 0; ww < 4; ++ww) v += spart[ww][ch >> 3][half * 8 + (ch & 7)];
      atomicAdd(&stats1[half * 128 + ch], v);
    }
    return;
  } else {
    // BN1 + relu -> zS
#pragma unroll
    for (int i = 0; i < 8; ++i) {
      int ch = cg * 8 + i;
      float mean = stats1[ch] * inv_m;
      float var = stats1[128 + ch] * inv_m - mean * mean;
      float rs = rsqrtf(var + 1e-5f);
      float zz = (acc[i] - mean) * rs * g1v[ch] + b1v[ch];
      zS[k][ch] = fmaxf(zz, 0.f);
    }
    __syncthreads();
    for (int i = tid; i < 128 * 128; i += 256) bufA[i] = W2[i];
    __syncthreads();
    float u[8];
#pragma unroll
    for (int i = 0; i < 8; ++i) u[i] = 0.f;
    for (int j = 0; j < 128; ++j) {
      float zv = zS[k][j];
      const float4* wp = reinterpret_cast<const float4*>(&bufA[j * 128 + cg * 8]);
      float4 wa = wp[0], wb = wp[1];
      u[0] = fmaf(zv, wa.x, u[0]); u[1] = fmaf(zv, wa.y, u[1]);
      u[2] = fmaf(zv, wa.z, u[2]); u[3] = fmaf(zv, wa.w, u[3]);
      u[4] = fmaf(zv, wb.x, u[4]); u[5] = fmaf(zv, wb.y, u[5]);
      u[6] = fmaf(zv, wb.z, u[6]); u[7] = fmaf(zv, wb.w, u[7]);
    }

    if constexpr (PASS == 1) {
      float sq[8];
#pragma unroll
      for (int i = 0; i < 8; ++i) sq[i] = u[i] * u[i];
#pragma unroll
      for (int i = 0; i < 8; ++i) {
        u[i] += __shfl_xor(u[i], 16, 64); sq[i] += __shfl_xor(sq[i], 16, 64);
        u[i] += __shfl_xor(u[i], 32, 64); sq[i] += __shfl_xor(sq[i], 32, 64);
      }
      if (lane < 16) {
#pragma unroll
        for (int i = 0; i < 8; ++i) { spart[w][cg][i] = u[i]; spart[w][cg][8 + i] = sq[i]; }
      }
      __syncthreads();
      {
        int ch = tid & 127, half = tid >> 7;
        float v = 0.f;
#pragma unroll
        for (int ww = 0; ww < 4; ++ww) v += spart[ww][ch >> 3][half * 8 + (ch & 7)];
        atomicAdd(&stats2[half * 128 + ch], v);
      }
      return;
    } else {
      // BN2 + relu + max over K
      float v8[8];
#pragma unroll
      for (int i = 0; i < 8; ++i) {
        int ch = cg * 8 + i;
        float mean = stats2[ch] * inv_m;
        float var = stats2[128 + ch] * inv_m - mean * mean;
        float rs = rsqrtf(var + 1e-5f);
        float vv = (u[i] - mean) * rs * g2v[ch] + b2v[ch];
        v8[i] = fmaxf(vv, 0.f);
      }
#pragma unroll
      for (int i = 0; i < 8; ++i) {
        v8[i] = fmaxf(v8[i], __shfl_xor(v8[i], 16, 64));
        v8[i] = fmaxf(v8[i], __shfl_xor(v8[i], 32, 64));
      }
      if (lane < 16) {
#pragma unroll
        for (int i = 0; i < 8; ++i) spart[w][cg][i] = v8[i];
      }
      __syncthreads();
      if (tid < 128) {
        int ch = tid;
        float m = spart[0][ch >> 3][ch & 7];
#pragma unroll
        for (int ww = 1; ww < 4; ++ww) m = fmaxf(m, spart[ww][ch >> 3][ch & 7]);
        out_feat[(size_t)bs * 128 + ch] = m;
      }
    }
  }
}

extern "C" void kernel_launch(void* const* d_in, const int* in_sizes, int n_in,
                              void* d_out, int out_size, void* d_ws, size_t ws_size,
                              hipStream_t stream) {
  const float* xyz  = (const float*)d_in[0];
  const float* feat = (const float*)d_in[1];
  const float* W1   = (const float*)d_in[2];
  const float* g1   = (const float*)d_in[3];
  const float* b1   = (const float*)d_in[4];
  const float* W2   = (const float*)d_in[5];
  const float* g2   = (const float*)d_in[6];
  const float* b2   = (const float*)d_in[7];
  float* out = (float*)d_out;
  float* new_xyz = out;                              // [4,2048,3]
  float* out_feat = out + NBATCH * N_SAMP * 3;       // [4,2048,128]

  int* fps_i = (int*)d_ws;                           // [4,2048]
  int* knn_i = fps_i + NBATCH * N_SAMP;              // [4,2048,16]
  float* stats1 = (float*)(knn_i + NBATCH * N_SAMP * KNN_K);  // [256]
  float* stats2 = stats1 + 256;                      // [256]

  hipMemsetAsync(stats1, 0, 512 * sizeof(float), stream);
  hipLaunchKernelGGL(fps_kernel, dim3(NBATCH), dim3(512), 0, stream, xyz, fps_i, new_xyz);
  hipLaunchKernelGGL(knn_kernel, dim3((NBATCH * N_SAMP) / 4), dim3(256), 0, stream,
                     xyz, new_xyz, knn_i);
  hipLaunchKernelGGL((mlp_kernel<0>), dim3(NBATCH * N_SAMP), dim3(256), 0, stream,
                     xyz, feat, W1, g1, b1, W2, g2, b2, new_xyz, knn_i, stats1, stats2, out_feat);
  hipLaunchKernelGGL((mlp_kernel<1>), dim3(NBATCH * N_SAMP), dim3(256), 0, stream,
                     xyz, feat, W1, g1, b1, W2, g2, b2, new_xyz, knn_i, stats1, stats2, out_feat);
  hipLaunchKernelGGL((mlp_kernel<2>), dim3(NBATCH * N_SAMP), dim3(256), 0, stream,
                     xyz, feat, W1, g1, b1, W2, g2, b2, new_xyz, knn_i, stats1, stats2, out_feat);
}